// Round 4
// baseline (1199.677 us; speedup 1.0000x reference)
//
#include <hip/hip_runtime.h>
#include <math.h>

// B=8, N=1024, D=256, H=4, hd=64, k=153
// K1: f64-accurate projections stored f64 in ws (32 MB) [unchanged, known-good].
// K2: f32 adj GEMM (src in regs via readlane broadcast, tgt f64->f32 staged in LDS),
//     exact f32 radix select + +-eps guard band; band members re-ranked by exact
//     f64 dot from ws. Exact vs f64 reference since band halfwidth 6e-4 > 2*E,
//     E = worst |adj_f32 - adj_f64| < 1.8e-4.

#define KSEL 153u
#define EPSK 20133u  // 6e-4 * 2^25

__device__ __forceinline__ float gelu_f32(float x) {
    return 0.5f * x * (1.0f + erff(x * 0.70710678118654752f));
}

// monotonic f64->u64 key: larger double => larger key
__device__ __forceinline__ unsigned long long d2key(double v) {
    unsigned long long u = (unsigned long long)__double_as_longlong(v);
    return (u >> 63) ? ~u : (u | 0x8000000000000000ull);
}

// linear 32-bit monotone key; injective on f32 near |v|~9 (ulp 9.5e-7 >> 2^-25)
__device__ __forceinline__ unsigned lkey(float v) {
    double q = ((double)v + 64.0) * 33554432.0;  // 2^25
    q = fmax(q, 0.0);
    q = fmin(q, 4294967295.0);
    return (unsigned)q;
}

// wave-uniform broadcast from constant lane -> SGPR operand
__device__ __forceinline__ float bcast(float v, int l) {
    return __uint_as_float(__builtin_amdgcn_readlane(__float_as_uint(v), l));
}

// ---------------- K1: projections, f64 accumulate, f64 store ----------------
__global__ __launch_bounds__(256) void k1_proj(const float* __restrict__ x,
                                               const float* __restrict__ Wsrc,
                                               const float* __restrict__ Wtgt,
                                               double* __restrict__ ws) {
    __shared__ float xs[32 * 68];
    __shared__ float wsh[32 * 68];
    const int t = threadIdx.x;
    const int bx = blockIdx.x;
    const int by = blockIdx.y;
    const int col0 = (by & 3) * 64;
    const float* __restrict__ W = (by < 4) ? Wsrc : Wtgt;
    double* __restrict__ outp = ws + ((by < 4) ? 0 : 2097152);

    double acc[4][4];
#pragma unroll
    for (int i = 0; i < 4; ++i)
#pragma unroll
        for (int j = 0; j < 4; ++j) acc[i][j] = 0.0;

    const int m_loc = (t & 15) * 4;
    const int c_loc = (t >> 4) * 4;

    for (int kt = 0; kt < 8; ++kt) {
        __syncthreads();
#pragma unroll
        for (int it = 0; it < 2; ++it) {
            int f4 = t + 256 * it;
            int m = f4 >> 3, k4 = f4 & 7;
            float4 v = *reinterpret_cast<const float4*>(&x[(bx * 64 + m) * 256 + kt * 32 + 4 * k4]);
            xs[(4 * k4 + 0) * 68 + m] = v.x;
            xs[(4 * k4 + 1) * 68 + m] = v.y;
            xs[(4 * k4 + 2) * 68 + m] = v.z;
            xs[(4 * k4 + 3) * 68 + m] = v.w;
        }
#pragma unroll
        for (int it = 0; it < 2; ++it) {
            int f4 = t + 256 * it;
            int k = f4 >> 4, c4 = f4 & 15;
            *reinterpret_cast<float4*>(&wsh[k * 68 + 4 * c4]) =
                *reinterpret_cast<const float4*>(&W[(kt * 32 + k) * 256 + col0 + 4 * c4]);
        }
        __syncthreads();
#pragma unroll
        for (int kk = 0; kk < 32; ++kk) {
            float4 a = *reinterpret_cast<const float4*>(&xs[kk * 68 + m_loc]);
            float4 b = *reinterpret_cast<const float4*>(&wsh[kk * 68 + c_loc]);
            double ad[4] = {a.x, a.y, a.z, a.w};
            double bd[4] = {b.x, b.y, b.z, b.w};
#pragma unroll
            for (int i = 0; i < 4; ++i)
#pragma unroll
                for (int j = 0; j < 4; ++j) acc[i][j] += ad[i] * bd[j];
        }
    }
    const int h = by & 3;
#pragma unroll
    for (int i = 0; i < 4; ++i) {
        int m = bx * 64 + m_loc + i;
        int b = m >> 10, n = m & 1023;
        size_t base = ((size_t)((b * 4 + h) * 1024 + n)) * 64 + c_loc;
        double2 v01, v23;
        v01.x = acc[i][0]; v01.y = acc[i][1];
        v23.x = acc[i][2]; v23.y = acc[i][3];
        *reinterpret_cast<double2*>(&outp[base]) = v01;
        *reinterpret_cast<double2*>(&outp[base + 2]) = v23;
    }
}

// ---------------- K2: f32 adj GEMM + banded exact top-k + gelu ----------------
// grid 2048: bh = bx>>6, itile = bx&63 -> 16 rows. 256 thr = 4 waves, wave = 4 rows.
// vals[r][c]: row r0+r, col = lane + 64*c.
__global__ __launch_bounds__(256) void k2_fused(const double* __restrict__ srcT,
                                                const double* __restrict__ tgtT,
                                                float* __restrict__ out) {
    __shared__ float tgt_s[256 * 66];           // 67584 B, [col_local]*66 + d
    __shared__ unsigned hist[4][256];           // per-wave radix hist
    __shared__ unsigned cj[4][64];              // band candidate col ids
    __shared__ unsigned long long ckey[4][64];  // band candidate f64 keys
    __shared__ unsigned ccnt[4];

    const int t = threadIdx.x;
    const int lane = t & 63;
    const int wv = t >> 6;
    const int bh = blockIdx.x >> 6;
    const int itile = blockIdx.x & 63;
    const int row0 = itile * 16;
    const int r0 = 4 * wv;
    const size_t tgtBase = (size_t)bh * 65536;
    const size_t srcRow = ((size_t)bh * 1024 + row0 + r0) * 64;

    // wave's 4 src rows in registers: lane holds row (lane>>4), d = 4*(lane&15)..+3
    const int sr = lane >> 4;
    const int sq = (lane & 15) * 4;
    double2 a01 = *reinterpret_cast<const double2*>(&srcT[srcRow + sr * 64 + sq]);
    double2 a23 = *reinterpret_cast<const double2*>(&srcT[srcRow + sr * 64 + sq + 2]);
    const float s0 = (float)a01.x, s1 = (float)a01.y, s2 = (float)a23.x, s3 = (float)a23.y;

    float vals[4][16];
#pragma unroll
    for (int r = 0; r < 4; ++r)
#pragma unroll
        for (int c = 0; c < 16; ++c) vals[r][c] = 0.0f;

#pragma unroll
    for (int c4 = 0; c4 < 4; ++c4) {
        __syncthreads();  // previous chunk fully consumed
        // stage 256 cols x 64 d, f64 -> f32 (coalesced: 2 cols x 32 d2 per wave-inst)
#pragma unroll 8
        for (int it = 0; it < 32; ++it) {
            int f = it * 256 + t;
            int d2 = f & 31, cl = f >> 5;
            double2 v = *reinterpret_cast<const double2*>(
                &tgtT[tgtBase + (size_t)(c4 * 256 + cl) * 64 + 2 * d2]);
            float2 fv;
            fv.x = (float)v.x;
            fv.y = (float)v.y;
            *reinterpret_cast<float2*>(&tgt_s[cl * 66 + 2 * d2]) = fv;
        }
        __syncthreads();

#pragma unroll
        for (int d2 = 0; d2 < 32; ++d2) {
            float bx[4], by[4];
#pragma unroll
            for (int r = 0; r < 4; ++r) {
                const int L = (r << 4) | (d2 >> 1);
                bx[r] = bcast((d2 & 1) ? s2 : s0, L);
                by[r] = bcast((d2 & 1) ? s3 : s1, L);
            }
#pragma unroll
            for (int m = 0; m < 4; ++m) {
                float2 bv = *reinterpret_cast<const float2*>(&tgt_s[(lane + 64 * m) * 66 + 2 * d2]);
#pragma unroll
                for (int r = 0; r < 4; ++r) {
                    vals[r][c4 * 4 + m] = fmaf(bx[r], bv.x, vals[r][c4 * 4 + m]);
                    vals[r][c4 * 4 + m] = fmaf(by[r], bv.y, vals[r][c4 * 4 + m]);
                }
            }
        }
    }

    // ---------------- per-wave exact select (banded) + gelu write ----------------
    const size_t outBase = ((size_t)bh * 1024 + row0 + r0) * 1024;

#pragma unroll
    for (int ri = 0; ri < 4; ++ri) {
        unsigned ul[16];
#pragma unroll
        for (int m = 0; m < 16; ++m) ul[m] = lkey(vals[ri][m]);

        // full 4-pass radix: exact key of k-th largest f32 value
        unsigned prefA = 0u, maskA = 0u, rk = KSEL;
#pragma unroll 1
        for (int p = 3; p >= 0; --p) {
            const int sh = 8 * p;
            *reinterpret_cast<uint4*>(&hist[wv][4 * lane]) = make_uint4(0u, 0u, 0u, 0u);
            asm volatile("s_waitcnt lgkmcnt(0)" ::: "memory");
#pragma unroll
            for (int m = 0; m < 16; ++m) {
                if ((ul[m] & maskA) == prefA)
                    atomicAdd(&hist[wv][(ul[m] >> sh) & 255u], 1u);
            }
            asm volatile("s_waitcnt lgkmcnt(0)" ::: "memory");
            unsigned h0 = hist[wv][4 * lane + 0], h1 = hist[wv][4 * lane + 1];
            unsigned h2 = hist[wv][4 * lane + 2], h3 = hist[wv][4 * lane + 3];
            unsigned S = h0 + h1 + h2 + h3;
            unsigned inc = S;
#pragma unroll
            for (int off = 1; off < 64; off <<= 1) {
                unsigned o = __shfl_down(inc, off, 64);
                inc = (lane + off < 64) ? (inc + o) : inc;
            }
            unsigned above = inc - S;
            bool found = (above < rk) && (rk <= inc);
            unsigned long long bal = __ballot(found);
            int L = __ffsll(bal) - 1;
            unsigned hh[4];
            hh[0] = __shfl(h0, L, 64);
            hh[1] = __shfl(h1, L, 64);
            hh[2] = __shfl(h2, L, 64);
            hh[3] = __shfl(h3, L, 64);
            unsigned cum = __shfl(above, L, 64);
            int bsel = -1;
#pragma unroll
            for (int q = 3; q >= 0; --q) {
                if (bsel < 0) {
                    if (rk <= cum + hh[q]) {
                        bsel = q;
                        rk = rk - cum;
                    } else {
                        cum += hh[q];
                    }
                }
            }
            prefA |= (unsigned)(4 * L + bsel) << sh;
            maskA |= 0xFFu << sh;
        }

        const unsigned khi = prefA + EPSK;
        const unsigned klo = prefA - EPSK;

        int ch = 0, cb = 0;
#pragma unroll
        for (int m = 0; m < 16; ++m) {
            ch += (ul[m] > khi) ? 1 : 0;
            cb += (ul[m] >= klo && ul[m] <= khi) ? 1 : 0;
        }
#pragma unroll
        for (int off = 32; off; off >>= 1) {
            ch += __shfl_xor(ch, off, 64);
            cb += __shfl_xor(cb, off, 64);
        }
        const unsigned need = KSEL - (unsigned)ch;  // >= 1, <= band count
        const bool fastp = ((unsigned)cb == need);  // all band members selected

        unsigned long long selMask = 0ull;
        unsigned cidx[16];
        if (!fastp) {
            if (lane == 0) ccnt[wv] = 0u;
            asm volatile("s_waitcnt lgkmcnt(0)" ::: "memory");
#pragma unroll
            for (int m = 0; m < 16; ++m) {
                cidx[m] = 0xFFFFFFFFu;
                if (ul[m] >= klo && ul[m] <= khi) {
                    unsigned idx = atomicAdd(&ccnt[wv], 1u);
                    cidx[m] = idx;
                    if (idx < 64u) cj[wv][idx] = (unsigned)(lane + 64 * m);
                }
            }
            asm volatile("s_waitcnt lgkmcnt(0)" ::: "memory");
            unsigned g = ccnt[wv];
            if (g > 64u) g = 64u;
            unsigned rnk = need;  // default: not selected
            if (lane < (int)g) {
                unsigned j = cj[wv][lane];
                const double* sp = &srcT[((size_t)bh * 1024 + row0 + r0 + ri) * 64];
                const double* tp = &tgtT[tgtBase + (size_t)j * 64];
                double acc = 0.0;
#pragma unroll 8
                for (int d = 0; d < 64; ++d) acc = fma(sp[d], tp[d], acc);
                ckey[wv][lane] = d2key(acc);
            }
            asm volatile("s_waitcnt lgkmcnt(0)" ::: "memory");
            if (lane < (int)g) {
                unsigned long long myk = ckey[wv][lane];
                unsigned myj = cj[wv][lane];
                rnk = 0;
                for (unsigned i = 0; i < g; ++i) {
                    unsigned long long ki = ckey[wv][i];
                    rnk += (ki > myk || (ki == myk && cj[wv][i] < myj)) ? 1u : 0u;
                }
            }
            selMask = __ballot(lane < (int)g && rnk < need);
        }

        const size_t rowBase = outBase + (size_t)ri * 1024;
#pragma unroll
        for (int m = 0; m < 16; ++m) {
            bool sel;
            if (ul[m] > khi) sel = true;
            else if (ul[m] < klo) sel = false;
            else sel = fastp ? true
                             : ((cidx[m] < 64u) ? (((selMask >> cidx[m]) & 1ull) != 0ull) : false);
            out[rowBase + (unsigned)(lane + 64 * m)] = sel ? gelu_f32(vals[ri][m]) : 0.0f;
        }
    }
}

extern "C" void kernel_launch(void* const* d_in, const int* in_sizes, int n_in,
                              void* d_out, int out_size, void* d_ws, size_t ws_size,
                              hipStream_t stream) {
    const float* x = (const float*)d_in[0];
    const float* Wsrc = (const float*)d_in[1];
    const float* Wtgt = (const float*)d_in[2];
    float* out = (float*)d_out;
    double* ws = (double*)d_ws;  // 32MB: src_t f64 (16MB) + tgt_t f64 (16MB)

    dim3 g1(128, 8);
    k1_proj<<<g1, 256, 0, stream>>>(x, Wsrc, Wtgt, ws);
    k2_fused<<<2048, 256, 0, stream>>>(ws, ws + 2097152, out);
}

// Round 5
// 236.686 us; speedup vs baseline: 5.0686x; 5.0686x over previous
//
#include <hip/hip_runtime.h>
#include <math.h>

// B=8, N=1024, D=256, H=4, hd=64, k=153
// K1: f64 projections -> ws (32 MB) + tgt f32 tiled copy (8 MB) if ws allows.
// K2: f32 adj GEMM (src LDS uniform-broadcast, tgt global_load_lds dbuf),
//     exact f32 radix select + eps band; band re-ranked by exact f64 dot.

#define KSEL 153u
#define EPSK 20133u  // 6e-4 * 2^25

__device__ __forceinline__ float gelu_f32(float x) {
    return 0.5f * x * (1.0f + erff(x * 0.70710678118654752f));
}

__device__ __forceinline__ unsigned long long d2key(double v) {
    unsigned long long u = (unsigned long long)__double_as_longlong(v);
    return (u >> 63) ? ~u : (u | 0x8000000000000000ull);
}

// linear 32-bit monotone key (|adj| < 64 guaranteed; sigma=8)
__device__ __forceinline__ unsigned lkey(float v) {
    double q = ((double)v + 64.0) * 33554432.0;  // 2^25
    q = fmax(q, 0.0);
    q = fmin(q, 4294967295.0);
    return (unsigned)q;
}

__device__ __forceinline__ void gload_lds16(const float* g, float* l) {
    __builtin_amdgcn_global_load_lds(
        (const __attribute__((address_space(1))) void*)g,
        (__attribute__((address_space(3))) void*)l, 16, 0, 0);
}

// ---------------- K1: projections, f64 accumulate, f64 (+tiled f32 tgt) store ----------------
template <bool W32>
__global__ __launch_bounds__(256) void k1_proj(const float* __restrict__ x,
                                               const float* __restrict__ Wsrc,
                                               const float* __restrict__ Wtgt,
                                               double* __restrict__ ws,
                                               float* __restrict__ t32) {
    __shared__ float xs[32 * 68];
    __shared__ float wsh[32 * 68];
    const int t = threadIdx.x;
    const int bx = blockIdx.x;
    const int by = blockIdx.y;
    const int col0 = (by & 3) * 64;
    const float* __restrict__ W = (by < 4) ? Wsrc : Wtgt;
    double* __restrict__ outp = ws + ((by < 4) ? 0 : 2097152);

    double acc[4][4];
#pragma unroll
    for (int i = 0; i < 4; ++i)
#pragma unroll
        for (int j = 0; j < 4; ++j) acc[i][j] = 0.0;

    const int m_loc = (t & 15) * 4;
    const int c_loc = (t >> 4) * 4;

    for (int kt = 0; kt < 8; ++kt) {
        __syncthreads();
#pragma unroll
        for (int it = 0; it < 2; ++it) {
            int f4 = t + 256 * it;
            int m = f4 >> 3, k4 = f4 & 7;
            float4 v = *reinterpret_cast<const float4*>(&x[(bx * 64 + m) * 256 + kt * 32 + 4 * k4]);
            xs[(4 * k4 + 0) * 68 + m] = v.x;
            xs[(4 * k4 + 1) * 68 + m] = v.y;
            xs[(4 * k4 + 2) * 68 + m] = v.z;
            xs[(4 * k4 + 3) * 68 + m] = v.w;
        }
#pragma unroll
        for (int it = 0; it < 2; ++it) {
            int f4 = t + 256 * it;
            int k = f4 >> 4, c4 = f4 & 15;
            *reinterpret_cast<float4*>(&wsh[k * 68 + 4 * c4]) =
                *reinterpret_cast<const float4*>(&W[(kt * 32 + k) * 256 + col0 + 4 * c4]);
        }
        __syncthreads();
#pragma unroll
        for (int kk = 0; kk < 32; ++kk) {
            float4 a = *reinterpret_cast<const float4*>(&xs[kk * 68 + m_loc]);
            float4 b = *reinterpret_cast<const float4*>(&wsh[kk * 68 + c_loc]);
            double ad[4] = {a.x, a.y, a.z, a.w};
            double bd[4] = {b.x, b.y, b.z, b.w};
#pragma unroll
            for (int i = 0; i < 4; ++i)
#pragma unroll
                for (int j = 0; j < 4; ++j) acc[i][j] += ad[i] * bd[j];
        }
    }
    const int h = by & 3;
#pragma unroll
    for (int i = 0; i < 4; ++i) {
        int m = bx * 64 + m_loc + i;
        int b = m >> 10, n = m & 1023;
        int bh = b * 4 + h;
        size_t base = ((size_t)(bh * 1024 + n)) * 64 + c_loc;
        double2 v01, v23;
        v01.x = acc[i][0]; v01.y = acc[i][1];
        v23.x = acc[i][2]; v23.y = acc[i][3];
        *reinterpret_cast<double2*>(&outp[base]) = v01;
        *reinterpret_cast<double2*>(&outp[base + 2]) = v23;
        if (W32 && by >= 4) {
            float4 f;
            f.x = (float)acc[i][0];
            f.y = (float)acc[i][1];
            f.z = (float)acc[i][2];
            f.w = (float)acc[i][3];
            // tiled: [bh][d4=c_loc/4][col=n][4]
            *reinterpret_cast<float4*>(&t32[((size_t)(bh * 16 + (c_loc >> 2)) * 1024 + n) * 4]) = f;
        }
    }
}

// ---------------- K2: f32 adj GEMM + banded exact top-k + gelu ----------------
// grid 2048: bh = bx>>6, itile = bx&63 -> 16 rows x 1024 cols. 4 waves, wave = 4 rows.
// vals[r][m]: row r0+r, col = lane + 64*m (all 1024 cols live per thread).
template <bool FAST>
__global__ __launch_bounds__(256, 3) void k2_fused(const double* __restrict__ srcT,
                                                   const double* __restrict__ tgtT,
                                                   const float* __restrict__ t32,
                                                   float* __restrict__ out) {
    __shared__ float tgt_s[2][4096];              // 2 x 16KB: [col][4 d] per d4 slice
    __shared__ float src_s[16][64];               // 4KB
    __shared__ __align__(16) unsigned hist[4][256];  // 4KB; per-wave; overlaid by cand arrays

    const int t = threadIdx.x;
    const int lane = t & 63;
    const int wv = t >> 6;
    const int bh = blockIdx.x >> 6;
    const int itile = blockIdx.x & 63;
    const int row0 = itile * 16;
    const int r0 = 4 * wv;
    const size_t tgtBase = (size_t)bh * 65536;
    const float* __restrict__ t32bh = t32 + (size_t)bh * 65536;

    // stage src rows f64 -> f32 LDS
    {
        int r = t >> 4, dq = (t & 15) * 4;
        const double* sp = &srcT[((size_t)bh * 1024 + row0 + r) * 64 + dq];
        double2 a = *reinterpret_cast<const double2*>(sp);
        double2 b = *reinterpret_cast<const double2*>(sp + 2);
        src_s[r][dq + 0] = (float)a.x;
        src_s[r][dq + 1] = (float)a.y;
        src_s[r][dq + 2] = (float)b.x;
        src_s[r][dq + 3] = (float)b.y;
    }

    float vals[4][16];
#pragma unroll
    for (int r = 0; r < 4; ++r)
#pragma unroll
        for (int m = 0; m < 16; ++m) vals[r][m] = 0.0f;

    double2 sU[4], sV[4];  // NONFAST staging regs (T14 split)

    if (FAST) {
#pragma unroll
        for (int i = 0; i < 4; ++i) {
            int seg = wv * 4 + i;
            gload_lds16(t32bh + 0 * 4096 + seg * 256 + lane * 4, &tgt_s[0][seg * 256]);
        }
    } else {
#pragma unroll
        for (int i = 0; i < 4; ++i) {
            int c = t + 256 * i;
            const double* gp = &tgtT[tgtBase + (size_t)c * 64 + 0];
            sU[i] = *reinterpret_cast<const double2*>(gp);
            sV[i] = *reinterpret_cast<const double2*>(gp + 2);
        }
#pragma unroll
        for (int i = 0; i < 4; ++i) {
            int c = t + 256 * i;
            float4 f;
            f.x = (float)sU[i].x; f.y = (float)sU[i].y;
            f.z = (float)sV[i].x; f.w = (float)sV[i].y;
            *reinterpret_cast<float4*>(&tgt_s[0][c * 4]) = f;
        }
    }
    __syncthreads();

#pragma unroll 1
    for (int d4 = 0; d4 < 16; ++d4) {
        const int cur = d4 & 1;
        // issue next-slice stage before compute
        if (d4 < 15) {
            if (FAST) {
#pragma unroll
                for (int i = 0; i < 4; ++i) {
                    int seg = wv * 4 + i;
                    gload_lds16(t32bh + (d4 + 1) * 4096 + seg * 256 + lane * 4,
                                &tgt_s[cur ^ 1][seg * 256]);
                }
            } else {
#pragma unroll
                for (int i = 0; i < 4; ++i) {
                    int c = t + 256 * i;
                    const double* gp = &tgtT[tgtBase + (size_t)c * 64 + (d4 + 1) * 4];
                    sU[i] = *reinterpret_cast<const double2*>(gp);
                    sV[i] = *reinterpret_cast<const double2*>(gp + 2);
                }
            }
        }
        // compute current slice
        float4 a[4];
#pragma unroll
        for (int r = 0; r < 4; ++r)
            a[r] = *reinterpret_cast<const float4*>(&src_s[r0 + r][d4 * 4]);
#pragma unroll
        for (int m = 0; m < 16; ++m) {
            float4 tv = *reinterpret_cast<const float4*>(&tgt_s[cur][(lane + 64 * m) * 4]);
#pragma unroll
            for (int r = 0; r < 4; ++r) {
                vals[r][m] = fmaf(a[r].x, tv.x, vals[r][m]);
                vals[r][m] = fmaf(a[r].y, tv.y, vals[r][m]);
                vals[r][m] = fmaf(a[r].z, tv.z, vals[r][m]);
                vals[r][m] = fmaf(a[r].w, tv.w, vals[r][m]);
            }
        }
        if (!FAST && d4 < 15) {
#pragma unroll
            for (int i = 0; i < 4; ++i) {
                int c = t + 256 * i;
                float4 f;
                f.x = (float)sU[i].x; f.y = (float)sU[i].y;
                f.z = (float)sV[i].x; f.w = (float)sV[i].y;
                *reinterpret_cast<float4*>(&tgt_s[cur ^ 1][c * 4]) = f;
            }
        }
        __syncthreads();  // compiler drains vmcnt/lgkmcnt before s_barrier
    }

    // ---------------- per-wave exact select (banded) + gelu write ----------------
    const size_t outBase = ((size_t)bh * 1024 + row0 + r0) * 1024;
    unsigned* cjp = &hist[wv][128];
    unsigned long long* ckp = reinterpret_cast<unsigned long long*>(&hist[wv][0]);
    unsigned* ccp = &hist[wv][192];

#pragma unroll
    for (int ri = 0; ri < 4; ++ri) {
        unsigned ul[16];
#pragma unroll
        for (int m = 0; m < 16; ++m) ul[m] = lkey(vals[ri][m]);

        unsigned prefA = 0u, maskA = 0u, rk = KSEL;
#pragma unroll 1
        for (int p = 3; p >= 0; --p) {
            const int sh = 8 * p;
            *reinterpret_cast<uint4*>(&hist[wv][4 * lane]) = make_uint4(0u, 0u, 0u, 0u);
            asm volatile("s_waitcnt lgkmcnt(0)" ::: "memory");
#pragma unroll
            for (int m = 0; m < 16; ++m) {
                if ((ul[m] & maskA) == prefA)
                    atomicAdd(&hist[wv][(ul[m] >> sh) & 255u], 1u);
            }
            asm volatile("s_waitcnt lgkmcnt(0)" ::: "memory");
            unsigned h0 = hist[wv][4 * lane + 0], h1 = hist[wv][4 * lane + 1];
            unsigned h2 = hist[wv][4 * lane + 2], h3 = hist[wv][4 * lane + 3];
            unsigned S = h0 + h1 + h2 + h3;
            unsigned inc = S;
#pragma unroll
            for (int off = 1; off < 64; off <<= 1) {
                unsigned o = __shfl_down(inc, off, 64);
                inc = (lane + off < 64) ? (inc + o) : inc;
            }
            unsigned above = inc - S;
            bool found = (above < rk) && (rk <= inc);
            unsigned long long bal = __ballot(found);
            int L = __ffsll(bal) - 1;
            unsigned hh[4];
            hh[0] = __shfl(h0, L, 64);
            hh[1] = __shfl(h1, L, 64);
            hh[2] = __shfl(h2, L, 64);
            hh[3] = __shfl(h3, L, 64);
            unsigned cum = __shfl(above, L, 64);
            int bsel = -1;
#pragma unroll
            for (int q = 3; q >= 0; --q) {
                if (bsel < 0) {
                    if (rk <= cum + hh[q]) {
                        bsel = q;
                        rk = rk - cum;
                    } else {
                        cum += hh[q];
                    }
                }
            }
            prefA |= (unsigned)(4 * L + bsel) << sh;
            maskA |= 0xFFu << sh;
        }

        const unsigned khi = prefA + EPSK;
        const unsigned klo = prefA - EPSK;

        int ch = 0, cb = 0;
#pragma unroll
        for (int m = 0; m < 16; ++m) {
            ch += (ul[m] > khi) ? 1 : 0;
            cb += (ul[m] >= klo && ul[m] <= khi) ? 1 : 0;
        }
#pragma unroll
        for (int off = 32; off; off >>= 1) {
            ch += __shfl_xor(ch, off, 64);
            cb += __shfl_xor(cb, off, 64);
        }
        const unsigned need = KSEL - (unsigned)ch;
        const bool fastp = ((unsigned)cb == need);

        unsigned long long selMask = 0ull;
        unsigned cidx[16];
        if (!fastp) {
            if (lane == 0) *ccp = 0u;
            asm volatile("s_waitcnt lgkmcnt(0)" ::: "memory");
#pragma unroll
            for (int m = 0; m < 16; ++m) {
                cidx[m] = 0xFFFFFFFFu;
                if (ul[m] >= klo && ul[m] <= khi) {
                    unsigned idx = atomicAdd(ccp, 1u);
                    cidx[m] = idx;
                    if (idx < 64u) cjp[idx] = (unsigned)(lane + 64 * m);
                }
            }
            asm volatile("s_waitcnt lgkmcnt(0)" ::: "memory");
            unsigned g = *ccp;
            if (g > 64u) g = 64u;
            unsigned rnk = need;
            if (lane < (int)g) {
                unsigned j = cjp[lane];
                const double* sp = &srcT[((size_t)bh * 1024 + row0 + r0 + ri) * 64];
                const double* tp = &tgtT[tgtBase + (size_t)j * 64];
                double acc = 0.0;
#pragma unroll 8
                for (int d = 0; d < 64; ++d) acc = fma(sp[d], tp[d], acc);
                ckp[lane] = d2key(acc);
            }
            asm volatile("s_waitcnt lgkmcnt(0)" ::: "memory");
            if (lane < (int)g) {
                unsigned long long myk = ckp[lane];
                unsigned myj = cjp[lane];
                rnk = 0;
                for (unsigned i = 0; i < g; ++i) {
                    unsigned long long ki = ckp[i];
                    rnk += (ki > myk || (ki == myk && cjp[i] < myj)) ? 1u : 0u;
                }
            }
            selMask = __ballot(lane < (int)g && rnk < need);
        }

        const size_t rowBase = outBase + (size_t)ri * 1024;
#pragma unroll
        for (int m = 0; m < 16; ++m) {
            bool sel;
            if (ul[m] > khi) sel = true;
            else if (ul[m] < klo) sel = false;
            else sel = fastp ? true
                             : ((cidx[m] < 64u) ? (((selMask >> cidx[m]) & 1ull) != 0ull) : false);
            out[rowBase + (unsigned)(lane + 64 * m)] = sel ? gelu_f32(vals[ri][m]) : 0.0f;
        }
    }
}

extern "C" void kernel_launch(void* const* d_in, const int* in_sizes, int n_in,
                              void* d_out, int out_size, void* d_ws, size_t ws_size,
                              hipStream_t stream) {
    const float* x = (const float*)d_in[0];
    const float* Wsrc = (const float*)d_in[1];
    const float* Wtgt = (const float*)d_in[2];
    float* out = (float*)d_out;
    double* ws = (double*)d_ws;                              // 32MB f64
    float* t32 = (float*)((char*)d_ws + 33554432);           // +8MB tiled f32 tgt

    const bool fast = (ws_size >= 40u * 1024u * 1024u);
    dim3 g1(128, 8);
    if (fast) {
        k1_proj<true><<<g1, 256, 0, stream>>>(x, Wsrc, Wtgt, ws, t32);
        k2_fused<true><<<2048, 256, 0, stream>>>(ws, ws + 2097152, t32, out);
    } else {
        k1_proj<false><<<g1, 256, 0, stream>>>(x, Wsrc, Wtgt, ws, t32);
        k2_fused<false><<<2048, 256, 0, stream>>>(ws, ws + 2097152, t32, out);
    }
}

// Round 7
// 187.403 us; speedup vs baseline: 6.4016x; 1.2630x over previous
//
#include <hip/hip_runtime.h>
#include <math.h>

// B=8, N=1024, D=256, H=4, hd=64, k=153
// K1: f64 projections -> ws (32 MB); tgt also emitted as bf16 hi/lo (4+4 MB).
// K2: split-bf16 MFMA adj GEMM (adj = Ah*Bh + Ah*Bl + Al*Bh, err <= ~9e-4),
//     LDS transpose to row-per-wave layout, 2-pass radix (bits 31:16) top-k +
//     eps band; band re-ranked by exact f64 dot from ws. gelu: x>3 -> x.

#define KSEL 153u
#define EPSK 61000u  // ~1.8e-3 * 2^25; certified adj err ~9e-4 -> 2x margin

typedef __attribute__((ext_vector_type(8))) short short8v;
typedef __attribute__((ext_vector_type(4))) float float4v;

__device__ __forceinline__ float gelu_f32(float x) {
    return 0.5f * x * (1.0f + erff(x * 0.70710678118654752f));
}

__device__ __forceinline__ unsigned long long d2key(double v) {
    unsigned long long u = (unsigned long long)__double_as_longlong(v);
    return (u >> 63) ? ~u : (u | 0x8000000000000000ull);
}

// monotone f32 -> u32 key: (v+64)*2^25 (f32-rounded; 128-key quantum << EPSK)
__device__ __forceinline__ unsigned lkeyf(float v) {
    float q = fmaf(v, 33554432.0f, 2147483648.0f);
    q = fminf(fmaxf(q, 0.0f), 4294967040.0f);
    return (unsigned)q;
}

__device__ __forceinline__ unsigned short b16(float x) {
    unsigned u = __float_as_uint(x);
    u += 0x7FFFu + ((u >> 16) & 1u);
    return (unsigned short)(u >> 16);
}
__device__ __forceinline__ float bf2f(unsigned short h) {
    return __uint_as_float(((unsigned)h) << 16);
}
__device__ __forceinline__ unsigned pk2(float a, float b) {
    return (unsigned)b16(a) | ((unsigned)b16(b) << 16);
}

__device__ __forceinline__ void gload16(const unsigned short* g, const char* l) {
    __builtin_amdgcn_global_load_lds(
        (const __attribute__((address_space(1))) void*)g,
        (__attribute__((address_space(3))) void*)l, 16, 0, 0);
}

// ---------------- K1: projections, f64 accumulate; tgt also bf16 hi/lo ----------------
template <bool W32>
__global__ __launch_bounds__(256) void k1_proj(const float* __restrict__ x,
                                               const float* __restrict__ Wsrc,
                                               const float* __restrict__ Wtgt,
                                               double* __restrict__ ws,
                                               unsigned short* __restrict__ th,
                                               unsigned short* __restrict__ tl) {
    __shared__ float xs[32 * 68];
    __shared__ float wsh[32 * 68];
    const int t = threadIdx.x;
    const int bx = blockIdx.x;
    const int by = blockIdx.y;
    const int col0 = (by & 3) * 64;
    const float* __restrict__ W = (by < 4) ? Wsrc : Wtgt;
    double* __restrict__ outp = ws + ((by < 4) ? 0 : 2097152);

    double acc[4][4];
#pragma unroll
    for (int i = 0; i < 4; ++i)
#pragma unroll
        for (int j = 0; j < 4; ++j) acc[i][j] = 0.0;

    const int m_loc = (t & 15) * 4;
    const int c_loc = (t >> 4) * 4;

    for (int kt = 0; kt < 8; ++kt) {
        __syncthreads();
#pragma unroll
        for (int it = 0; it < 2; ++it) {
            int f4 = t + 256 * it;
            int m = f4 >> 3, k4 = f4 & 7;
            float4 v = *reinterpret_cast<const float4*>(&x[(bx * 64 + m) * 256 + kt * 32 + 4 * k4]);
            xs[(4 * k4 + 0) * 68 + m] = v.x;
            xs[(4 * k4 + 1) * 68 + m] = v.y;
            xs[(4 * k4 + 2) * 68 + m] = v.z;
            xs[(4 * k4 + 3) * 68 + m] = v.w;
        }
#pragma unroll
        for (int it = 0; it < 2; ++it) {
            int f4 = t + 256 * it;
            int k = f4 >> 4, c4 = f4 & 15;
            *reinterpret_cast<float4*>(&wsh[k * 68 + 4 * c4]) =
                *reinterpret_cast<const float4*>(&W[(kt * 32 + k) * 256 + col0 + 4 * c4]);
        }
        __syncthreads();
#pragma unroll
        for (int kk = 0; kk < 32; ++kk) {
            float4 a = *reinterpret_cast<const float4*>(&xs[kk * 68 + m_loc]);
            float4 b = *reinterpret_cast<const float4*>(&wsh[kk * 68 + c_loc]);
            double ad[4] = {a.x, a.y, a.z, a.w};
            double bd[4] = {b.x, b.y, b.z, b.w};
#pragma unroll
            for (int i = 0; i < 4; ++i)
#pragma unroll
                for (int j = 0; j < 4; ++j) acc[i][j] += ad[i] * bd[j];
        }
    }
    const int hd = by & 3;
#pragma unroll
    for (int i = 0; i < 4; ++i) {
        int m = bx * 64 + m_loc + i;
        int b = m >> 10, n = m & 1023;
        int bhd = b * 4 + hd;
        size_t base = ((size_t)(bhd * 1024 + n)) * 64 + c_loc;
        double2 v01, v23;
        v01.x = acc[i][0]; v01.y = acc[i][1];
        v23.x = acc[i][2]; v23.y = acc[i][3];
        *reinterpret_cast<double2*>(&outp[base]) = v01;
        *reinterpret_cast<double2*>(&outp[base + 2]) = v23;
        if (W32 && by >= 4) {
            float f0 = (float)acc[i][0], f1 = (float)acc[i][1];
            float f2 = (float)acc[i][2], f3 = (float)acc[i][3];
            unsigned short h0 = b16(f0), h1 = b16(f1), h2 = b16(f2), h3 = b16(f3);
            uint2 H, L;
            H.x = (unsigned)h0 | ((unsigned)h1 << 16);
            H.y = (unsigned)h2 | ((unsigned)h3 << 16);
            L.x = pk2(f0 - bf2f(h0), f1 - bf2f(h1));
            L.y = pk2(f2 - bf2f(h2), f3 - bf2f(h3));
            *reinterpret_cast<uint2*>(&th[base]) = H;
            *reinterpret_cast<uint2*>(&tl[base]) = L;
        }
    }
}

// ---------------- K2: split-bf16 MFMA GEMM + transpose + banded top-k ----------------
// grid 2048: bh = bx>>6, itile = bx&63 -> 16 rows x 1024 cols. 4 waves.
// Chunks of 128 cols; wave computes tiles {wv, wv+4} per chunk. After GEMM,
// C is transposed via LDS to vals[4][16] (wave owns rows 4wv..+3, col=lane+64m).
template <bool FAST>
__global__ __launch_bounds__(256, 2) void k2_fused(const double* __restrict__ srcT,
                                                   const double* __restrict__ tgtT,
                                                   const unsigned short* __restrict__ th,
                                                   const unsigned short* __restrict__ tlo,
                                                   float* __restrict__ out) {
    __shared__ __align__(16) char smem[65536];   // staging (2x32KB dbuf) / transpose f32[16][1024]
    __shared__ unsigned short srcf[2][1024];     // src hi/lo, slot-swizzled
    __shared__ __align__(16) unsigned hist[4][256];

    const int t = threadIdx.x;
    const int lane = t & 63;
    const int wv = t >> 6;
    const int bh = blockIdx.x >> 6;
    const int itile = blockIdx.x & 63;
    const int row0 = itile * 16;
    const int r0 = 4 * wv;
    const size_t tgtBase = (size_t)bh * 65536;
    const unsigned short* __restrict__ thb = th + tgtBase;
    const unsigned short* __restrict__ tlb = tlo + tgtBase;

    // ---- src rows f64 -> bf16 hi/lo into swizzled srcf ----
    {
        int r = t >> 4, dq = (t & 15) * 4;
        const double* sp = &srcT[((size_t)bh * 1024 + row0 + r) * 64 + dq];
        double2 a = *reinterpret_cast<const double2*>(sp);
        double2 b = *reinterpret_cast<const double2*>(sp + 2);
        float f0 = (float)a.x, f1 = (float)a.y, f2 = (float)b.x, f3 = (float)b.y;
        unsigned short h0 = b16(f0), h1 = b16(f1), h2 = b16(f2), h3 = b16(f3);
        int s = dq >> 3;
        int idx = r * 64 + ((s ^ (r & 7)) << 3) + (dq & 7);
        uint2 H, L;
        H.x = (unsigned)h0 | ((unsigned)h1 << 16);
        H.y = (unsigned)h2 | ((unsigned)h3 << 16);
        L.x = pk2(f0 - bf2f(h0), f1 - bf2f(h1));
        L.y = pk2(f2 - bf2f(h2), f3 - bf2f(h3));
        *reinterpret_cast<uint2*>(&srcf[0][idx]) = H;
        *reinterpret_cast<uint2*>(&srcf[1][idx]) = L;
    }

    // ---- staging helpers ----
    const int soffu = (lane >> 3) * 64 + (((lane & 7) ^ (lane >> 3)) << 3);  // pre-swizzled src offset

#define STAGE_FAST(cn, b)                                                              \
    {                                                                                  \
        _Pragma("unroll") for (int q = 0; q < 4; ++q) {                                \
            int i = 4 * wv + q;                                                        \
            gload16(thb + (size_t)((cn) * 128 + 8 * i) * 64 + soffu,                   \
                    smem + (b) * 32768 + i * 1024);                                    \
            gload16(tlb + (size_t)((cn) * 128 + 8 * i) * 64 + soffu,                   \
                    smem + (b) * 32768 + 16384 + i * 1024);                            \
        }                                                                              \
    }

#define STAGE_SLOW(cn, b)                                                              \
    {                                                                                  \
        _Pragma("unroll") for (int it = 0; it < 4; ++it) {                             \
            int sid = t + 256 * it;                                                    \
            int cl = sid >> 3, s = sid & 7;                                            \
            const double* gp = &tgtT[tgtBase + (size_t)((cn) * 128 + cl) * 64 + s * 8];\
            double2 d0 = *reinterpret_cast<const double2*>(gp);                        \
            double2 d1 = *reinterpret_cast<const double2*>(gp + 2);                    \
            double2 d2 = *reinterpret_cast<const double2*>(gp + 4);                    \
            double2 d3 = *reinterpret_cast<const double2*>(gp + 6);                    \
            float f[8] = {(float)d0.x, (float)d0.y, (float)d1.x, (float)d1.y,          \
                          (float)d2.x, (float)d2.y, (float)d3.x, (float)d3.y};         \
            unsigned short hh[8];                                                      \
            _Pragma("unroll") for (int e = 0; e < 8; ++e) hh[e] = b16(f[e]);           \
            uint4 H, L;                                                                \
            H.x = (unsigned)hh[0] | ((unsigned)hh[1] << 16);                           \
            H.y = (unsigned)hh[2] | ((unsigned)hh[3] << 16);                           \
            H.z = (unsigned)hh[4] | ((unsigned)hh[5] << 16);                           \
            H.w = (unsigned)hh[6] | ((unsigned)hh[7] << 16);                           \
            L.x = pk2(f[0] - bf2f(hh[0]), f[1] - bf2f(hh[1]));                         \
            L.y = pk2(f[2] - bf2f(hh[2]), f[3] - bf2f(hh[3]));                         \
            L.z = pk2(f[4] - bf2f(hh[4]), f[5] - bf2f(hh[5]));                         \
            L.w = pk2(f[6] - bf2f(hh[6]), f[7] - bf2f(hh[7]));                         \
            int widx = cl * 64 + ((s ^ (cl & 7)) << 3);                                \
            *reinterpret_cast<uint4*>((unsigned short*)(smem + (b) * 32768) + widx) = H;\
            *reinterpret_cast<uint4*>((unsigned short*)(smem + (b) * 32768 + 16384) + widx) = L;\
        }                                                                              \
    }

    if (FAST) STAGE_FAST(0, 0) else STAGE_SLOW(0, 0);
    __syncthreads();  // srcf ready + chunk0 staged (vmcnt drained at barrier)

    // ---- hoist A fragments ----
    short8v Ah[2], Al[2];
#pragma unroll
    for (int ks = 0; ks < 2; ++ks) {
        int idxA = (lane & 15) * 64 + (((4 * ks + (lane >> 4)) ^ (lane & 7)) << 3);
        Ah[ks] = *reinterpret_cast<const short8v*>(&srcf[0][idxA]);
        Al[ks] = *reinterpret_cast<const short8v*>(&srcf[1][idxA]);
    }

    float4v acc[16];
#pragma unroll
    for (int a = 0; a < 16; ++a) acc[a] = (float4v){0.f, 0.f, 0.f, 0.f};

#pragma unroll
    for (int c = 0; c < 8; ++c) {
        const int buf = c & 1;
        if (c < 7) {
            if (FAST) STAGE_FAST(c + 1, buf ^ 1) else STAGE_SLOW(c + 1, buf ^ 1);
        }
        const unsigned short* bph = (const unsigned short*)(smem + buf * 32768);
        const unsigned short* bpl = (const unsigned short*)(smem + buf * 32768 + 16384);
#pragma unroll
        for (int u = 0; u < 2; ++u) {
            const int tlc = wv + 4 * u;
            const int A = 2 * c + u;
            const int cl = 16 * tlc + (lane & 15);
#pragma unroll
            for (int ks = 0; ks < 2; ++ks) {
                int idxB = cl * 64 + (((4 * ks + (lane >> 4)) ^ (cl & 7)) << 3);
                short8v Bh = *reinterpret_cast<const short8v*>(&bph[idxB]);
                short8v Bl = *reinterpret_cast<const short8v*>(&bpl[idxB]);
                acc[A] = __builtin_amdgcn_mfma_f32_16x16x32_bf16(Ah[ks], Bh, acc[A], 0, 0, 0);
                acc[A] = __builtin_amdgcn_mfma_f32_16x16x32_bf16(Al[ks], Bh, acc[A], 0, 0, 0);
                acc[A] = __builtin_amdgcn_mfma_f32_16x16x32_bf16(Ah[ks], Bl, acc[A], 0, 0, 0);
            }
        }
        __syncthreads();
    }

    // ---- transpose C through LDS to row-per-wave layout ----
    float* tr = (float*)smem;
#pragma unroll
    for (int c = 0; c < 8; ++c)
#pragma unroll
        for (int u = 0; u < 2; ++u) {
            int T = 8 * c + wv + 4 * u;
            int A = 2 * c + u;
#pragma unroll
            for (int reg = 0; reg < 4; ++reg) {
                int row = 4 * (lane >> 4) + reg;
                int colx = (16 * T + (lane & 15)) ^ ((lane >> 4) << 4);
                tr[row * 1024 + colx] = acc[A][reg];
            }
        }
    __syncthreads();

    float vals[4][16];
#pragma unroll
    for (int ri = 0; ri < 4; ++ri)
#pragma unroll
        for (int m = 0; m < 16; ++m)
            vals[ri][m] = tr[(r0 + ri) * 1024 + ((lane + 64 * m) ^ (wv << 4))];

    // ---------------- per-wave exact select (banded) + gelu write ----------------
    const size_t outBase = ((size_t)bh * 1024 + row0 + r0) * 1024;
    unsigned* cjp = &hist[wv][128];
    unsigned long long* ckp = reinterpret_cast<unsigned long long*>(&hist[wv][0]);
    unsigned* ccp = &hist[wv][192];

#pragma unroll
    for (int ri = 0; ri < 4; ++ri) {
        unsigned ul[16];
#pragma unroll
        for (int m = 0; m < 16; ++m) ul[m] = lkeyf(vals[ri][m]);

        // 2-pass radix on top 16 bits (bits 31:24, then 23:16)
        unsigned prefA = 0u, maskA = 0u, rk = KSEL;
#pragma unroll 1
        for (int p = 1; p >= 0; --p) {
            const int sh = 16 + 8 * p;  // p=1 -> 24, p=0 -> 16
            *reinterpret_cast<uint4*>(&hist[wv][4 * lane]) = make_uint4(0u, 0u, 0u, 0u);
            asm volatile("s_waitcnt lgkmcnt(0)" ::: "memory");
#pragma unroll
            for (int m = 0; m < 16; ++m) {
                if ((ul[m] & maskA) == prefA)
                    atomicAdd(&hist[wv][(ul[m] >> sh) & 255u], 1u);
            }
            asm volatile("s_waitcnt lgkmcnt(0)" ::: "memory");
            unsigned h0 = hist[wv][4 * lane + 0], h1 = hist[wv][4 * lane + 1];
            unsigned h2 = hist[wv][4 * lane + 2], h3 = hist[wv][4 * lane + 3];
            unsigned S = h0 + h1 + h2 + h3;
            unsigned inc = S;
#pragma unroll
            for (int off = 1; off < 64; off <<= 1) {
                unsigned o = __shfl_down(inc, off, 64);
                inc = (lane + off < 64) ? (inc + o) : inc;
            }
            unsigned above = inc - S;
            bool found = (above < rk) && (rk <= inc);
            unsigned long long bal = __ballot(found);
            int L = __ffsll(bal) - 1;
            unsigned hh[4];
            hh[0] = __shfl(h0, L, 64);
            hh[1] = __shfl(h1, L, 64);
            hh[2] = __shfl(h2, L, 64);
            hh[3] = __shfl(h3, L, 64);
            unsigned cum = __shfl(above, L, 64);
            int bsel = -1;
#pragma unroll
            for (int q = 3; q >= 0; --q) {
                if (bsel < 0) {
                    if (rk <= cum + hh[q]) {
                        bsel = q;
                        rk = rk - cum;
                    } else {
                        cum += hh[q];
                    }
                }
            }
            prefA |= (unsigned)(4 * L + bsel) << sh;
            maskA |= 0xFFu << sh;
        }

        // band: k-th key in [prefA, prefA+0xFFFF]; ambiguity halfwidth EPSK
        const unsigned klo = prefA - EPSK;
        const unsigned khi = prefA + 65535u + EPSK;

        int ch = 0, cb = 0;
#pragma unroll
        for (int m = 0; m < 16; ++m) {
            ch += (ul[m] > khi) ? 1 : 0;
            cb += (ul[m] >= klo && ul[m] <= khi) ? 1 : 0;
        }
#pragma unroll
        for (int off = 32; off; off >>= 1) {
            ch += __shfl_xor(ch, off, 64);
            cb += __shfl_xor(cb, off, 64);
        }
        const unsigned need = KSEL - (unsigned)ch;
        const bool fastp = ((unsigned)cb == need);

        unsigned long long selMask = 0ull;
        unsigned cidx[16];
        if (!fastp) {
            if (lane == 0) *ccp = 0u;
            asm volatile("s_waitcnt lgkmcnt(0)" ::: "memory");
#pragma unroll
            for (int m = 0; m < 16; ++m) {
                cidx[m] = 0xFFFFFFFFu;
                if (ul[m] >= klo && ul[m] <= khi) {
                    unsigned idx = atomicAdd(ccp, 1u);
                    cidx[m] = idx;
                    if (idx < 64u) cjp[idx] = (unsigned)(lane + 64 * m);
                }
            }
            asm volatile("s_waitcnt lgkmcnt(0)" ::: "memory");
            unsigned g = *ccp;
            if (g > 64u) g = 64u;
            unsigned rnk = need;
            if (lane < (int)g) {
                unsigned j = cjp[lane];
                const double2* sp = reinterpret_cast<const double2*>(
                    &srcT[((size_t)bh * 1024 + row0 + r0 + ri) * 64]);
                const double2* tp = reinterpret_cast<const double2*>(&tgtT[tgtBase + (size_t)j * 64]);
                double a2 = 0.0;
#pragma unroll 8
                for (int d2 = 0; d2 < 32; ++d2) {
                    double2 aa = sp[d2], bb = tp[d2];
                    a2 = fma(aa.x, bb.x, fma(aa.y, bb.y, a2));
                }
                ckp[lane] = d2key(a2);
            }
            asm volatile("s_waitcnt lgkmcnt(0)" ::: "memory");
            if (lane < (int)g) {
                unsigned long long myk = ckp[lane];
                unsigned myj = cjp[lane];
                rnk = 0;
                for (unsigned i = 0; i < g; ++i) {
                    unsigned long long ki = ckp[i];
                    rnk += (ki > myk || (ki == myk && cjp[i] < myj)) ? 1u : 0u;
                }
            }
            selMask = __ballot(lane < (int)g && rnk < need);
        }

        const size_t rowBase = outBase + (size_t)ri * 1024;
#pragma unroll
        for (int m = 0; m < 16; ++m) {
            bool sel;
            if (ul[m] > khi) sel = true;
            else if (ul[m] < klo) sel = false;
            else sel = fastp ? true
                             : ((cidx[m] < 64u) ? (((selMask >> cidx[m]) & 1ull) != 0ull) : false);
            float v = vals[ri][m];
            float g = 0.0f;
            if (sel) g = (v > 3.0f) ? v : gelu_f32(v);
            out[rowBase + (unsigned)(lane + 64 * m)] = g;
        }
    }
}

extern "C" void kernel_launch(void* const* d_in, const int* in_sizes, int n_in,
                              void* d_out, int out_size, void* d_ws, size_t ws_size,
                              hipStream_t stream) {
    const float* x = (const float*)d_in[0];
    const float* Wsrc = (const float*)d_in[1];
    const float* Wtgt = (const float*)d_in[2];
    float* out = (float*)d_out;
    double* ws = (double*)d_ws;                                      // 32MB f64
    unsigned short* th = (unsigned short*)((char*)d_ws + 33554432);  // +4MB tgt hi
    unsigned short* tl = (unsigned short*)((char*)d_ws + 37748736);  // +4MB tgt lo

    const bool fast = (ws_size >= 40u * 1024u * 1024u);
    dim3 g1(128, 8);
    if (fast) {
        k1_proj<true><<<g1, 256, 0, stream>>>(x, Wsrc, Wtgt, ws, th, tl);
        k2_fused<true><<<2048, 256, 0, stream>>>(ws, ws + 2097152, th, tl, out);
    } else {
        k1_proj<false><<<g1, 256, 0, stream>>>(x, Wsrc, Wtgt, ws, th, tl);
        k2_fused<false><<<2048, 256, 0, stream>>>(ws, ws + 2097152, th, tl, out);
    }
}

// Round 9
// 179.522 us; speedup vs baseline: 6.6826x; 1.0439x over previous
//
#include <hip/hip_runtime.h>
#include <math.h>

// B=8, N=1024, D=256, H=4, hd=64, k=153
// K1: f64 projections -> ws (32 MB); tgt also emitted as bf16 hi/lo (4+4 MB).
// K2: split-bf16 MFMA adj GEMM, B-frags direct from global (L2-resident),
//     TWO half-passes over cols (acc[8] reused -> no VGPR spill at 3 blocks/CU),
//     2-half LDS transpose (32KB) -> 40KB LDS. 2-pass radix (bits 31:16) top-k
//     + eps band; band re-ranked by exact f64 dot from ws. gelu: x>3 -> x.

#define KSEL 153u
#define EPSK 61000u  // ~1.8e-3 * 2^25; certified adj err ~9e-4 -> 2x margin

typedef __attribute__((ext_vector_type(8))) short short8v;
typedef __attribute__((ext_vector_type(4))) float float4v;

__device__ __forceinline__ float gelu_f32(float x) {
    return 0.5f * x * (1.0f + erff(x * 0.70710678118654752f));
}

__device__ __forceinline__ unsigned long long d2key(double v) {
    unsigned long long u = (unsigned long long)__double_as_longlong(v);
    return (u >> 63) ? ~u : (u | 0x8000000000000000ull);
}

// monotone f32 -> u32 key: (v+64)*2^25 (f32-rounded; 128-key quantum << EPSK)
__device__ __forceinline__ unsigned lkeyf(float v) {
    float q = fmaf(v, 33554432.0f, 2147483648.0f);
    q = fminf(fmaxf(q, 0.0f), 4294967040.0f);
    return (unsigned)q;
}

__device__ __forceinline__ unsigned short b16(float x) {
    unsigned u = __float_as_uint(x);
    u += 0x7FFFu + ((u >> 16) & 1u);
    return (unsigned short)(u >> 16);
}
__device__ __forceinline__ float bf2f(unsigned short h) {
    return __uint_as_float(((unsigned)h) << 16);
}
__device__ __forceinline__ unsigned pk2(float a, float b) {
    return (unsigned)b16(a) | ((unsigned)b16(b) << 16);
}

#define LGKM0()                                             \
    do {                                                    \
        asm volatile("s_waitcnt lgkmcnt(0)" ::: "memory");  \
        __builtin_amdgcn_sched_barrier(0);                  \
    } while (0)

// ---------------- K1: projections, f64 accumulate; tgt also bf16 hi/lo ----------------
template <bool W32>
__global__ __launch_bounds__(256) void k1_proj(const float* __restrict__ x,
                                               const float* __restrict__ Wsrc,
                                               const float* __restrict__ Wtgt,
                                               double* __restrict__ ws,
                                               unsigned short* __restrict__ th,
                                               unsigned short* __restrict__ tl) {
    __shared__ float xs[32 * 68];
    __shared__ float wsh[32 * 68];
    const int t = threadIdx.x;
    const int bx = blockIdx.x;
    const int by = blockIdx.y;
    const int col0 = (by & 3) * 64;
    const float* __restrict__ W = (by < 4) ? Wsrc : Wtgt;
    double* __restrict__ outp = ws + ((by < 4) ? 0 : 2097152);

    double acc[4][4];
#pragma unroll
    for (int i = 0; i < 4; ++i)
#pragma unroll
        for (int j = 0; j < 4; ++j) acc[i][j] = 0.0;

    const int m_loc = (t & 15) * 4;
    const int c_loc = (t >> 4) * 4;

    for (int kt = 0; kt < 8; ++kt) {
        __syncthreads();
#pragma unroll
        for (int it = 0; it < 2; ++it) {
            int f4 = t + 256 * it;
            int m = f4 >> 3, k4 = f4 & 7;
            float4 v = *reinterpret_cast<const float4*>(&x[(bx * 64 + m) * 256 + kt * 32 + 4 * k4]);
            xs[(4 * k4 + 0) * 68 + m] = v.x;
            xs[(4 * k4 + 1) * 68 + m] = v.y;
            xs[(4 * k4 + 2) * 68 + m] = v.z;
            xs[(4 * k4 + 3) * 68 + m] = v.w;
        }
#pragma unroll
        for (int it = 0; it < 2; ++it) {
            int f4 = t + 256 * it;
            int k = f4 >> 4, c4 = f4 & 15;
            *reinterpret_cast<float4*>(&wsh[k * 68 + 4 * c4]) =
                *reinterpret_cast<const float4*>(&W[(kt * 32 + k) * 256 + col0 + 4 * c4]);
        }
        __syncthreads();
#pragma unroll
        for (int kk = 0; kk < 32; ++kk) {
            float4 a = *reinterpret_cast<const float4*>(&xs[kk * 68 + m_loc]);
            float4 b = *reinterpret_cast<const float4*>(&wsh[kk * 68 + c_loc]);
            double ad[4] = {a.x, a.y, a.z, a.w};
            double bd[4] = {b.x, b.y, b.z, b.w};
#pragma unroll
            for (int i = 0; i < 4; ++i)
#pragma unroll
                for (int j = 0; j < 4; ++j) acc[i][j] += ad[i] * bd[j];
        }
    }
    const int hd = by & 3;
#pragma unroll
    for (int i = 0; i < 4; ++i) {
        int m = bx * 64 + m_loc + i;
        int b = m >> 10, n = m & 1023;
        int bhd = b * 4 + hd;
        size_t base = ((size_t)(bhd * 1024 + n)) * 64 + c_loc;
        double2 v01, v23;
        v01.x = acc[i][0]; v01.y = acc[i][1];
        v23.x = acc[i][2]; v23.y = acc[i][3];
        *reinterpret_cast<double2*>(&outp[base]) = v01;
        *reinterpret_cast<double2*>(&outp[base + 2]) = v23;
        if (W32 && by >= 4) {
            float f0 = (float)acc[i][0], f1 = (float)acc[i][1];
            float f2 = (float)acc[i][2], f3 = (float)acc[i][3];
            unsigned short h0 = b16(f0), h1 = b16(f1), h2 = b16(f2), h3 = b16(f3);
            uint2 H, L;
            H.x = (unsigned)h0 | ((unsigned)h1 << 16);
            H.y = (unsigned)h2 | ((unsigned)h3 << 16);
            L.x = pk2(f0 - bf2f(h0), f1 - bf2f(h1));
            L.y = pk2(f2 - bf2f(h2), f3 - bf2f(h3));
            *reinterpret_cast<uint2*>(&th[base]) = H;
            *reinterpret_cast<uint2*>(&tl[base]) = L;
        }
    }
}

// ---------------- K2: direct-B MFMA GEMM (2 half-passes) + banded top-k ----------------
// grid 2048 (XCD-swizzled): bh = id>>6, itile = id&63 -> 16 rows x 1024 cols.
// 4 waves. Per half h: wave computes tiles T = 32h + 4u + wv (u=0..7) into acc[8],
// transposes via 32KB LDS to vals[4][8h..8h+7] (wave owns rows 4wv..+3, col=lane+64m).
template <bool FAST>
__global__ __launch_bounds__(256, 3) void k2_fused(const double* __restrict__ srcT,
                                                   const double* __restrict__ tgtT,
                                                   const unsigned short* __restrict__ th,
                                                   const unsigned short* __restrict__ tlo,
                                                   float* __restrict__ out) {
    __shared__ float tr[16 * 512];                   // 32KB transpose buffer
    __shared__ unsigned short srcf[2][1024];         // 4KB src hi/lo, slot-swizzled
    __shared__ __align__(16) unsigned hist[4][256];  // 4KB per-wave

    const int t = threadIdx.x;
    const int lane = t & 63;
    const int wv = t >> 6;
    const int bid = (blockIdx.x & 7) * 256 + (blockIdx.x >> 3);  // XCD swizzle (2048 % 8 == 0)
    const int bh = bid >> 6;
    const int itile = bid & 63;
    const int row0 = itile * 16;
    const int r0 = 4 * wv;
    const size_t tgtBase = (size_t)bh * 65536;
    const unsigned short* __restrict__ thb = th + tgtBase;
    const unsigned short* __restrict__ tlb = tlo + tgtBase;

    // ---- src rows f64 -> bf16 hi/lo into swizzled srcf ----
    {
        int r = t >> 4, dq = (t & 15) * 4;
        const double* sp = &srcT[((size_t)bh * 1024 + row0 + r) * 64 + dq];
        double2 a = *reinterpret_cast<const double2*>(sp);
        double2 b = *reinterpret_cast<const double2*>(sp + 2);
        float f0 = (float)a.x, f1 = (float)a.y, f2 = (float)b.x, f3 = (float)b.y;
        unsigned short h0 = b16(f0), h1 = b16(f1), h2 = b16(f2), h3 = b16(f3);
        int s = dq >> 3;
        int idx = r * 64 + ((s ^ (r & 7)) << 3) + (dq & 7);
        uint2 H, L;
        H.x = (unsigned)h0 | ((unsigned)h1 << 16);
        H.y = (unsigned)h2 | ((unsigned)h3 << 16);
        L.x = pk2(f0 - bf2f(h0), f1 - bf2f(h1));
        L.y = pk2(f2 - bf2f(h2), f3 - bf2f(h3));
        *reinterpret_cast<uint2*>(&srcf[0][idx]) = H;
        *reinterpret_cast<uint2*>(&srcf[1][idx]) = L;
    }
    __syncthreads();

    // ---- hoist A fragments (k-octet s' = 4ks + (lane>>4), XOR-swizzled store) ----
    short8v Ah[2], Al[2];
#pragma unroll
    for (int ks = 0; ks < 2; ++ks) {
        int idxA = (lane & 15) * 64 + (((4 * ks + (lane >> 4)) ^ (lane & 7)) << 3);
        Ah[ks] = *reinterpret_cast<const short8v*>(&srcf[0][idxA]);
        Al[ks] = *reinterpret_cast<const short8v*>(&srcf[1][idxA]);
    }

    const int colA = lane & 15;
    const int kgrp = lane >> 4;
    float vals[4][16];

#pragma unroll
    for (int h = 0; h < 2; ++h) {
        // ---- GEMM half: cols 512h..512h+511, acc[8] ----
        float4v acc[8];
#pragma unroll
        for (int a = 0; a < 8; ++a) acc[a] = (float4v){0.f, 0.f, 0.f, 0.f};

#pragma unroll
        for (int u = 0; u < 8; ++u) {
            const int T = 32 * h + 4 * u + wv;
            const size_t cbase = (size_t)(16 * T + colA) * 64 + kgrp * 8;
#pragma unroll
            for (int ks = 0; ks < 2; ++ks) {
                short8v Bh, Bl;
                if (FAST) {
                    Bh = *reinterpret_cast<const short8v*>(&thb[cbase + 32 * ks]);
                    Bl = *reinterpret_cast<const short8v*>(&tlb[cbase + 32 * ks]);
                } else {
                    const double* gp = &tgtT[tgtBase + cbase + 32 * ks];
                    double2 d0 = *reinterpret_cast<const double2*>(gp);
                    double2 d1 = *reinterpret_cast<const double2*>(gp + 2);
                    double2 d2 = *reinterpret_cast<const double2*>(gp + 4);
                    double2 d3 = *reinterpret_cast<const double2*>(gp + 6);
                    float f[8] = {(float)d0.x, (float)d0.y, (float)d1.x, (float)d1.y,
                                  (float)d2.x, (float)d2.y, (float)d3.x, (float)d3.y};
                    unsigned short hh[8];
#pragma unroll
                    for (int e = 0; e < 8; ++e) hh[e] = b16(f[e]);
                    unsigned Hw[4], Lw[4];
#pragma unroll
                    for (int e = 0; e < 4; ++e) {
                        Hw[e] = (unsigned)hh[2 * e] | ((unsigned)hh[2 * e + 1] << 16);
                        Lw[e] = pk2(f[2 * e] - bf2f(hh[2 * e]), f[2 * e + 1] - bf2f(hh[2 * e + 1]));
                    }
                    Bh = *reinterpret_cast<const short8v*>(Hw);
                    Bl = *reinterpret_cast<const short8v*>(Lw);
                }
                acc[u] = __builtin_amdgcn_mfma_f32_16x16x32_bf16(Ah[ks], Bh, acc[u], 0, 0, 0);
                acc[u] = __builtin_amdgcn_mfma_f32_16x16x32_bf16(Al[ks], Bh, acc[u], 0, 0, 0);
                acc[u] = __builtin_amdgcn_mfma_f32_16x16x32_bf16(Ah[ks], Bl, acc[u], 0, 0, 0);
            }
        }

        // ---- transpose half through 32KB LDS ----
        __syncthreads();  // h=0: after srcf/A reads; h=1: all half-0 tr reads done
#pragma unroll
        for (int u = 0; u < 8; ++u) {
            int colh = 16 * (4 * u + wv) + colA;  // 0..511 within half
#pragma unroll
            for (int reg = 0; reg < 4; ++reg) {
                int row = 4 * kgrp + reg;
                tr[row * 512 + (colh ^ ((row & 1) << 4))] = acc[u][reg];
            }
        }
        __syncthreads();
#pragma unroll
        for (int ri = 0; ri < 4; ++ri) {
            int row = r0 + ri;
#pragma unroll
            for (int mm = 0; mm < 8; ++mm) {
                int colh = lane + 64 * mm;
                vals[ri][8 * h + mm] = tr[row * 512 + (colh ^ ((row & 1) << 4))];
            }
        }
    }

    // ---------------- per-wave exact select (banded) + gelu write ----------------
    const size_t outBase = ((size_t)bh * 1024 + row0 + r0) * 1024;
    unsigned* cjp = &hist[wv][128];
    unsigned long long* ckp = reinterpret_cast<unsigned long long*>(&hist[wv][0]);
    unsigned* ccp = &hist[wv][192];

#pragma unroll
    for (int ri = 0; ri < 4; ++ri) {
        unsigned ul[16];
#pragma unroll
        for (int m = 0; m < 16; ++m) ul[m] = lkeyf(vals[ri][m]);

        // 2-pass radix on top 16 bits (bits 31:24, then 23:16)
        unsigned prefA = 0u, maskA = 0u, rk = KSEL;
#pragma unroll 1
        for (int p = 1; p >= 0; --p) {
            const int sh = 16 + 8 * p;
            *reinterpret_cast<uint4*>(&hist[wv][4 * lane]) = make_uint4(0u, 0u, 0u, 0u);
            LGKM0();
#pragma unroll
            for (int m = 0; m < 16; ++m) {
                if ((ul[m] & maskA) == prefA)
                    atomicAdd(&hist[wv][(ul[m] >> sh) & 255u], 1u);
            }
            LGKM0();
            unsigned h0 = hist[wv][4 * lane + 0], h1 = hist[wv][4 * lane + 1];
            unsigned h2 = hist[wv][4 * lane + 2], h3 = hist[wv][4 * lane + 3];
            unsigned S = h0 + h1 + h2 + h3;
            unsigned inc = S;
#pragma unroll
            for (int off = 1; off < 64; off <<= 1) {
                unsigned o = __shfl_down(inc, off, 64);
                inc = (lane + off < 64) ? (inc + o) : inc;
            }
            unsigned above = inc - S;
            bool found = (above < rk) && (rk <= inc);
            unsigned long long bal = __ballot(found);
            int L = __ffsll(bal) - 1;
            unsigned hh[4];
            hh[0] = __shfl(h0, L, 64);
            hh[1] = __shfl(h1, L, 64);
            hh[2] = __shfl(h2, L, 64);
            hh[3] = __shfl(h3, L, 64);
            unsigned cum = __shfl(above, L, 64);
            int bsel = -1;
#pragma unroll
            for (int q = 3; q >= 0; --q) {
                if (bsel < 0) {
                    if (rk <= cum + hh[q]) {
                        bsel = q;
                        rk = rk - cum;
                    } else {
                        cum += hh[q];
                    }
                }
            }
            prefA |= (unsigned)(4 * L + bsel) << sh;
            maskA |= 0xFFu << sh;
        }

        // band: k-th key in [prefA, prefA+0xFFFF]; ambiguity halfwidth EPSK
        const unsigned klo = prefA - EPSK;
        const unsigned khi = prefA + 65535u + EPSK;

        int ch = 0, cb = 0;
#pragma unroll
        for (int m = 0; m < 16; ++m) {
            ch += (ul[m] > khi) ? 1 : 0;
            cb += (ul[m] >= klo && ul[m] <= khi) ? 1 : 0;
        }
#pragma unroll
        for (int off = 32; off; off >>= 1) {
            ch += __shfl_xor(ch, off, 64);
            cb += __shfl_xor(cb, off, 64);
        }
        const unsigned need = KSEL - (unsigned)ch;
        const bool fastp = ((unsigned)cb == need);

        unsigned long long selMask = 0ull;
        unsigned cidx[16];
        if (!fastp) {
            if (lane == 0) *ccp = 0u;
            LGKM0();
#pragma unroll
            for (int m = 0; m < 16; ++m) {
                cidx[m] = 0xFFFFFFFFu;
                if (ul[m] >= klo && ul[m] <= khi) {
                    unsigned idx = atomicAdd(ccp, 1u);
                    cidx[m] = idx;
                    if (idx < 64u) cjp[idx] = (unsigned)(lane + 64 * m);
                }
            }
            LGKM0();
            unsigned g = *ccp;
            if (g > 64u) g = 64u;
            unsigned rnk = need;
            if (lane < (int)g) {
                unsigned j = cjp[lane];
                const double2* sp = reinterpret_cast<const double2*>(
                    &srcT[((size_t)bh * 1024 + row0 + r0 + ri) * 64]);
                const double2* tp = reinterpret_cast<const double2*>(&tgtT[tgtBase + (size_t)j * 64]);
                double a2 = 0.0;
#pragma unroll 8
                for (int d2 = 0; d2 < 32; ++d2) {
                    double2 aa = sp[d2], bb = tp[d2];
                    a2 = fma(aa.x, bb.x, fma(aa.y, bb.y, a2));
                }
                ckp[lane] = d2key(a2);
            }
            LGKM0();
            if (lane < (int)g) {
                unsigned long long myk = ckp[lane];
                unsigned myj = cjp[lane];
                rnk = 0;
                for (unsigned i = 0; i < g; ++i) {
                    unsigned long long ki = ckp[i];
                    rnk += (ki > myk || (ki == myk && cjp[i] < myj)) ? 1u : 0u;
                }
            }
            selMask = __ballot(lane < (int)g && rnk < need);
        }

        const size_t rowBase = outBase + (size_t)ri * 1024;
#pragma unroll
        for (int m = 0; m < 16; ++m) {
            bool sel;
            if (ul[m] > khi) sel = true;
            else if (ul[m] < klo) sel = false;
            else sel = fastp ? true
                             : ((cidx[m] < 64u) ? (((selMask >> cidx[m]) & 1ull) != 0ull) : false);
            float v = vals[ri][m];
            float g = 0.0f;
            if (sel) g = (v > 3.0f) ? v : gelu_f32(v);
            out[rowBase + (unsigned)(lane + 64 * m)] = g;
        }
    }
}

extern "C" void kernel_launch(void* const* d_in, const int* in_sizes, int n_in,
                              void* d_out, int out_size, void* d_ws, size_t ws_size,
                              hipStream_t stream) {
    const float* x = (const float*)d_in[0];
    const float* Wsrc = (const float*)d_in[1];
    const float* Wtgt = (const float*)d_in[2];
    float* out = (float*)d_out;
    double* ws = (double*)d_ws;                                      // 32MB f64
    unsigned short* th = (unsigned short*)((char*)d_ws + 33554432);  // +4MB tgt hi
    unsigned short* tl = (unsigned short*)((char*)d_ws + 37748736);  // +4MB tgt lo

    const bool fast = (ws_size >= 40u * 1024u * 1024u);
    dim3 g1(128, 8);
    if (fast) {
        k1_proj<true><<<g1, 256, 0, stream>>>(x, Wsrc, Wtgt, ws, th, tl);
        k2_fused<true><<<2048, 256, 0, stream>>>(ws, ws + 2097152, th, tl, out);
    } else {
        k1_proj<false><<<g1, 256, 0, stream>>>(x, Wsrc, Wtgt, ws, th, tl);
        k2_fused<false><<<2048, 256, 0, stream>>>(ws, ws + 2097152, th, tl, out);
    }
}